// Round 1
// baseline (576.886 us; speedup 1.0000x reference)
//
#include <hip/hip_runtime.h>

#define D 64
#define KC 512        // number of codebook entries
#define EMA_A 0.01f   // 1 - EMA_DECAY
#define CROWS 8192    // rows per histogram block

typedef float v2f __attribute__((ext_vector_type(2)));

// ---------------- K0: ee[k] = sum_d emb[k][d]^2 ----------------
__global__ __launch_bounds__(256) void k_ee(const float* __restrict__ emb,
                                            float* __restrict__ ee) {
    int k = blockIdx.x * blockDim.x + threadIdx.x;
    if (k >= KC) return;
    float s = 0.f;
#pragma unroll
    for (int d = 0; d < D; ++d) { float e = emb[k * D + d]; s = fmaf(e, e, s); }
    ee[k] = s;
}

// ---------------- K1: per-row argmin over 512 clusters ----------------
// 2 rows per thread, v2f accumulators -> hope for v_pk_fma_f32.
// emb/ee indices are wave-uniform -> s_load, SGPR operand into the FMA.
__global__ __launch_bounds__(256, 2) void k_assign(
    const float* __restrict__ x, const float* __restrict__ emb,
    const float* __restrict__ ee, int* __restrict__ idx, int halfN) {
    int t = blockIdx.x * 256 + threadIdx.x;
    int n0 = t, n1 = t + halfN;
    float xr0[D], xr1[D];
    const float4* p0 = (const float4*)(x + (size_t)n0 * D);
    const float4* p1 = (const float4*)(x + (size_t)n1 * D);
#pragma unroll
    for (int i = 0; i < D / 4; ++i) {
        float4 a = p0[i];
        xr0[4 * i + 0] = a.x; xr0[4 * i + 1] = a.y;
        xr0[4 * i + 2] = a.z; xr0[4 * i + 3] = a.w;
    }
#pragma unroll
    for (int i = 0; i < D / 4; ++i) {
        float4 b = p1[i];
        xr1[4 * i + 0] = b.x; xr1[4 * i + 1] = b.y;
        xr1[4 * i + 2] = b.z; xr1[4 * i + 3] = b.w;
    }
    float xx0 = 0.f, xx1 = 0.f;
#pragma unroll
    for (int d = 0; d < D; ++d) {
        xx0 = fmaf(xr0[d], xr0[d], xx0);
        xx1 = fmaf(xr1[d], xr1[d], xx1);
    }
    float best0 = 3.4e38f, best1 = 3.4e38f;
    int bi0 = 0, bi1 = 0;
    for (int k0 = 0; k0 < KC; k0 += 8) {
        v2f s[8];
#pragma unroll
        for (int j = 0; j < 8; ++j) s[j] = (v2f){0.f, 0.f};
#pragma unroll
        for (int d = 0; d < D; ++d) {
            v2f xd; xd.x = xr0[d]; xd.y = xr1[d];
#pragma unroll
            for (int j = 0; j < 8; ++j)
                s[j] += xd * emb[(k0 + j) * D + d];   // uniform -> SGPR operand
        }
#pragma unroll
        for (int j = 0; j < 8; ++j) {
            float eek = ee[k0 + j];
            float d0 = xx0 - 2.0f * s[j].x + eek;
            float d1 = xx1 - 2.0f * s[j].y + eek;
            if (d0 < best0) { best0 = d0; bi0 = k0 + j; }  // strict < : first-min
            if (d1 < best1) { best1 = d1; bi1 = k0 + j; }  // tie-break = jnp.argmin
        }
    }
    idx[n0] = bi0;
    idx[n1] = bi1;
}

// ---------------- K2a: per-block histogram of cluster counts ----------------
__global__ __launch_bounds__(256) void k_count(const int* __restrict__ idx,
                                               float* __restrict__ gcount, int N) {
    __shared__ int hist[KC];
    int tid = threadIdx.x;
    for (int i = tid; i < KC; i += 256) hist[i] = 0;
    __syncthreads();
    int base = blockIdx.x * CROWS;
    int end = base + CROWS; if (end > N) end = N;
    for (int r = base + tid; r < end; r += 256) atomicAdd(&hist[idx[r]], 1);
    __syncthreads();
    for (int i = tid; i < KC; i += 256)
        gcount[(size_t)blockIdx.x * KC + i] = (float)hist[i];
}

// ---------------- K2b: LDS-privatized segment sums (two k-half passes) -------
// part[] is 64 KB (256 clusters x 64 d). Swizzle (d+k)&63 -> bank (d+k)%32 so
// lanes hitting different clusters spread across banks.
__global__ __launch_bounds__(256) void k_segsum(
    const float* __restrict__ x, const int* __restrict__ idx,
    float* __restrict__ gpart, int N, int P) {
    __shared__ float part[256 * D];  // 64 KB
    int tid = threadIdx.x;
    int chunk = (N + P - 1) / P;
    int base = blockIdx.x * chunk;
    int end = base + chunk; if (end > N) end = N;
    size_t ob = (size_t)blockIdx.x * (KC * D);
    for (int half = 0; half < 2; ++half) {
        for (int i = tid; i < 256 * D; i += 256) part[i] = 0.f;
        __syncthreads();
        for (int r = base + tid; r < end; r += 256) {
            int k = idx[r];
            if ((k >> 8) == half) {
                int kl = k & 255;
                const float4* p = (const float4*)(x + (size_t)r * D);
#pragma unroll
                for (int i = 0; i < D / 4; ++i) {
                    float4 v = p[i];
                    int d = 4 * i;
                    atomicAdd(&part[kl * D + ((d + 0 + kl) & 63)], v.x);
                    atomicAdd(&part[kl * D + ((d + 1 + kl) & 63)], v.y);
                    atomicAdd(&part[kl * D + ((d + 2 + kl) & 63)], v.z);
                    atomicAdd(&part[kl * D + ((d + 3 + kl) & 63)], v.w);
                }
            }
        }
        __syncthreads();
        for (int i = tid; i < 256 * D; i += 256) {
            int kl = i >> 6, d = i & 63;
            gpart[ob + (size_t)half * (256 * D) + i] = part[kl * D + ((d + kl) & 63)];
        }
        __syncthreads();
    }
}

// ---------------- K3a: reduce count partials ----------------
__global__ __launch_bounds__(256) void k_csum(const float* __restrict__ gcount,
                                              float* __restrict__ cfin, int nb) {
    int k = blockIdx.x * 256 + threadIdx.x;
    if (k >= KC) return;
    float s = 0.f;
    for (int b = 0; b < nb; ++b) s += gcount[(size_t)b * KC + k];
    cfin[k] = s;
}

// ---------------- K3b: reduce sum partials + EMA update -> embedding_new -----
// usage==0 clusters never appear in encoding_index, so flat[r] path is dead.
__global__ __launch_bounds__(256) void k_embnew(
    const float* __restrict__ gpart, const float* __restrict__ cfin,
    const float* __restrict__ cnt_in, const float* __restrict__ sum_embed,
    float* __restrict__ embnew, int P) {
    int i = blockIdx.x * 256 + threadIdx.x;  // < KC*D
    int k = i >> 6;
    float s = 0.f;
    for (int p = 0; p < P; ++p) s += gpart[(size_t)p * (KC * D) + i];
    float c = cfin[k];
    float c0 = cnt_in[k];
    float cn = c0 + EMA_A * (c - c0);
    float se0 = sum_embed[i];
    float se = se0 + EMA_A * (s - se0);
    bool used = (cn >= 1.0f);
    embnew[i] = used ? (se / cn) : 0.0f;  // unused entries are never gathered
}

// ---------------- K4: gather out[n][:] = embnew[idx[n]][:] ----------------
__global__ __launch_bounds__(256) void k_gather(const int* __restrict__ idx,
                                                const float* __restrict__ embnew,
                                                float* __restrict__ out, int N) {
    int g = blockIdx.x * 256 + threadIdx.x;  // N * 16 work items
    int row = g >> 4, q = g & 15;
    if (row >= N) return;
    int k = idx[row];
    const float4* e4 = (const float4*)embnew;
    ((float4*)out)[(size_t)row * (D / 4) + q] = e4[k * (D / 4) + q];
}

extern "C" void kernel_launch(void* const* d_in, const int* in_sizes, int n_in,
                              void* d_out, int out_size, void* d_ws, size_t ws_size,
                              hipStream_t stream) {
    const float* x = (const float*)d_in[0];
    const float* emb = (const float*)d_in[1];
    const float* cnt = (const float*)d_in[2];
    const float* sum_embed = (const float*)d_in[3];
    float* out = (float*)d_out;
    int N = in_sizes[0] / D;  // 262144

    char* w = (char*)d_ws;
    size_t off = 0;
    int* idx = (int*)(w + off);      off += (size_t)N * 4;
    float* ee = (float*)(w + off);   off += (size_t)KC * 4;
    float* cfin = (float*)(w + off); off += (size_t)KC * 4;
    float* embnew = (float*)(w + off); off += (size_t)KC * D * 4;
    int cblocks = (N + CROWS - 1) / CROWS;
    float* gcount = (float*)(w + off); off += (size_t)cblocks * KC * 4;
    size_t fixed = off;
    size_t perP = (size_t)KC * D * 4;
    int P = 256;
    if (ws_size > fixed) {
        size_t maxP = (ws_size - fixed) / perP;
        if ((size_t)P > maxP) P = (int)maxP;
    }
    if (P < 1) P = 1;
    float* gpart = (float*)(w + off);

    k_ee<<<(KC + 255) / 256, 256, 0, stream>>>(emb, ee);
    k_assign<<<(N / 2 + 255) / 256, 256, 0, stream>>>(x, emb, ee, idx, N / 2);
    k_count<<<cblocks, 256, 0, stream>>>(idx, gcount, N);
    k_segsum<<<P, 256, 0, stream>>>(x, idx, gpart, N, P);
    k_csum<<<(KC + 255) / 256, 256, 0, stream>>>(gcount, cfin, cblocks);
    k_embnew<<<(KC * D) / 256, 256, 0, stream>>>(gpart, cfin, cnt, sum_embed, embnew, P);
    k_gather<<<((size_t)N * (D / 4) + 255) / 256, 256, 0, stream>>>(idx, embnew, out, N);
}